// Round 5
// baseline (32090.585 us; speedup 1.0000x reference)
//
#include <hip/hip_runtime.h>

#define NB 256
#define NT 1024

// problem dims
#define BB   64
#define TTS  2048
#define DKV  128
#define EEM  256
#define HH1  512
#define VVV  30
#define LLS  256
#define SOS_ID 1
#define SCALE_F 0.088388347648318447f  // 1/sqrt(128)

// ws float offsets
#define OFF_PM2   0        // 512  slice partial max  [b*8+s]
#define OFF_PS2   512      // 512  slice partial sum  [b*8+s]
#define OFF_PCTX2 1024     // 65536 slice partial ctx [d*512 + b*8 + s]
#define OFF_WSE   66560    // 2048 energies for b=0
#define OFF_H1    68608    // 2*32768 h1 double buffer [k*64+b]
#define OFF_H2T   134144   // 2*8192 h2 transposed [d*64+b]
#define OFF_EP    150528   // 1024 uints: epA[256] @0, epB[64] @256, epC[256] @320
#define OFF_KBF   151552   // bf16 K: 16777216 ushorts
#define OFF_VBF   8540160  // bf16 V
#define WS_NEED_BYTES 67715072ull
#define PRED_SZ   491520   // 64*256*30

struct Params {
  const float* key; const float* value;
  const int* enc_len; const int* y;
  const float* emb;
  const float* Wih1; const float* Whh1; const float* bih1; const float* bhh1;
  const float* Wih2; const float* Whh2; const float* bih2; const float* bhh2;
  const float* obias;
  float* out; float* ws;
};

struct SMEM {
  union {
    struct {
      float ctxT[8192];                      // [d*64 + b], 32 KB
      union { float wt[8192]; float red[8192]; } u;
    } a;
    struct { float wm[16]; float wS[16]; float wctx[2048]; } c;
  };
};

__device__ __forceinline__ float sigm(float x) { return 1.f / (1.f + __expf(-x)); }
__device__ __forceinline__ float tanh_f(float x) {
  float t = __expf(-2.f * fabsf(x));
  float r = (1.f - t) / (1.f + t);
  return x < 0.f ? -r : r;
}
__device__ __forceinline__ unsigned bfr(float f) {  // fp32 -> bf16 bits, RNE
  unsigned u = __float_as_uint(f);
  return (u + 0x7FFFu + ((u >> 16) & 1u)) >> 16;
}
__device__ __forceinline__ float b2f(unsigned short h) {
  return __uint_as_float(((unsigned)h) << 16);
}
// L2-bypassing load (agent-scope atomic): sees fresh L3 data, leaves L2 intact.
__device__ __forceinline__ float ldg_f(const float* p) {
  return __hip_atomic_load(p, __ATOMIC_RELAXED, __HIP_MEMORY_SCOPE_AGENT);
}

// wait until all n epoch slots >= target; every wave polls independently.
__device__ __forceinline__ void wait_ep(const unsigned* slots, int n, unsigned target) {
  const int lane = threadIdx.x & 63;
  int guard = 0;
  for (;;) {
    bool ok = true;
    for (int j = lane; j < n; j += 64)
      ok &= (__hip_atomic_load(slots + j, __ATOMIC_RELAXED, __HIP_MEMORY_SCOPE_AGENT) >= target);
    if (__all(ok)) break;
    __builtin_amdgcn_s_sleep(1);
    if (++guard > 30000000) break;   // anti-deadlock bailout
  }
  // compiler-level ordering only; does NOT invalidate L2 (keeps KV warm)
  __builtin_amdgcn_fence(__ATOMIC_ACQUIRE, "workgroup");
}

// publish this block's phase: writeback dirty lines to L3, then epoch store.
__device__ __forceinline__ void post_ep(unsigned* slot, unsigned val) {
  __syncthreads();
  if (threadIdx.x == 0) {
    __builtin_amdgcn_fence(__ATOMIC_RELEASE, "agent");   // L2 writeback (no invalidate)
    __hip_atomic_store(slot, val, __ATOMIC_RELAXED, __HIP_MEMORY_SCOPE_AGENT);
  }
}

__device__ __forceinline__ void mac8x4(float acc[8][4], const float* wt, int k, float4 x4) {
  float4 wa = *(const float4*)(wt + k*8);
  float4 wb = *(const float4*)(wt + k*8 + 4);
  float wr[8] = {wa.x, wa.y, wa.z, wa.w, wb.x, wb.y, wb.z, wb.w};
  float xr[4] = {x4.x, x4.y, x4.z, x4.w};
  #pragma unroll
  for (int r = 0; r < 8; ++r)
    #pragma unroll
    for (int c = 0; c < 4; ++c)
      acc[r][c] += wr[r] * xr[c];
}

__device__ __forceinline__ void gate_reduce_store(float acc[8][4], float* red, int tid) {
  #pragma unroll
  for (int r = 0; r < 8; ++r) {
    #pragma unroll
    for (int c = 0; c < 4; ++c) {
      float v = acc[r][c];
      v += __shfl_xor(v, 16);
      v += __shfl_xor(v, 32);
      acc[r][c] = v;
    }
  }
  int wv = tid >> 6, b0 = tid & 15;
  if ((tid & 63) < 16) {
    #pragma unroll
    for (int r = 0; r < 8; ++r)
      *(float4*)(red + wv*512 + r*64 + b0*4) =
        make_float4(acc[r][0], acc[r][1], acc[r][2], acc[r][3]);
  }
}

// wave-partials -> block partial -> (pm2, pS2, pctx2) via normal stores
__device__ __forceinline__ void attn_combine(SMEM* sm, float m, float S, float4 ca,
                                             int lane, int w, int sub, int grp, int tid,
                                             float* pm2, float* pS2, float* pctx2,
                                             int bb, int s) {
  float mo = __shfl_xor(m, 32);
  float M2 = fmaxf(m, mo);
  float as_ = __expf(m - M2), ao = __expf(mo - M2);
  float S2 = S*as_ + __shfl_xor(S, 32)*ao;
  float cx = ca.x*as_ + __shfl_xor(ca.x, 32)*ao;
  float cy = ca.y*as_ + __shfl_xor(ca.y, 32)*ao;
  float cz = ca.z*as_ + __shfl_xor(ca.z, 32)*ao;
  float cw = ca.w*as_ + __shfl_xor(ca.w, 32)*ao;
  if (lane == 0) { sm->c.wm[w] = M2; sm->c.wS[w] = S2; }
  if (grp == 0)
    *(float4*)(sm->c.wctx + w*DKV + sub*4) = make_float4(cx, cy, cz, cw);
  __syncthreads();
  if (tid < DKV) {
    int d = tid;
    float M = -1e30f;
    #pragma unroll
    for (int ww = 0; ww < 16; ++ww) M = fmaxf(M, sm->c.wm[ww]);
    float Z = 0.f, acc2 = 0.f;
    #pragma unroll
    for (int ww = 0; ww < 16; ++ww) {
      float aw = __expf(sm->c.wm[ww] - M);
      Z += aw * sm->c.wS[ww];
      acc2 += aw * sm->c.wctx[ww*DKV + d];
    }
    pctx2[d*512 + bb*8 + s] = acc2;
    if (d == 0) { pm2[bb*8 + s] = M; pS2[bb*8 + s] = Z; }
  }
  __syncthreads();
}

// setup-only: mean over full T (fixed mapping b=bj>>2, s=bj&3), fp32 V normal loads
__device__ void phase_attn_mean(const Params& p, float* pm2, float* pS2, float* pctx2,
                                SMEM* sm, int bj, int tid) {
  const int lane = tid & 63, w = tid >> 6;
  const int b = bj >> 2, s = bj & 3;
  const int sub = lane & 31, grp = lane >> 5;
  float S = 0.f;
  float4 ca = make_float4(0.f, 0.f, 0.f, 0.f);
  const int t0 = (4*w + s) * 32;
  const float* vb = p.value + (size_t)b * TTS * DKV;
  for (int tt = 0; tt < 32; tt += 2) {
    int t = t0 + tt + grp;
    float4 v4 = *(const float4*)(vb + (size_t)t*DKV + sub*4);
    S += 1.f;
    ca.x += v4.x; ca.y += v4.y; ca.z += v4.z; ca.w += v4.w;
  }
  attn_combine(sm, 0.f, S, ca, lane, w, sub, grp, tid, pm2, pS2, pctx2, b, s);
}

// balanced online-softmax attention; KV via NORMAL loads (L2-resident!)
template<bool BF16>
__device__ void phase_attn_bal(const Params& p, const float* h2t,
                               const unsigned short* kbf, const unsigned short* vbf,
                               float* pm2, float* pS2, float* pctx2, float* wsE,
                               int bb, int s, int n, SMEM* sm, int tid) {
  const int lane = tid & 63, w = tid >> 6;
  const int sub = lane & 31, grp = lane >> 5;
  const int len = p.enc_len[bb];
  const int R = (len + 31) >> 5;
  const int s0 = (s*R)/n, s1 = ((s+1)*R)/n;
  const int ns = s1 - s0;
  // q via bypass loads (h2 written by B blocks this step)
  const float q0 = ldg_f(h2t + (sub*4+0)*64 + bb);
  const float q1 = ldg_f(h2t + (sub*4+1)*64 + bb);
  const float q2 = ldg_f(h2t + (sub*4+2)*64 + bb);
  const float q3 = ldg_f(h2t + (sub*4+3)*64 + bb);
  float m = -1e30f, S = 0.f;
  float4 ca = make_float4(0.f, 0.f, 0.f, 0.f);
  const int rbase = s0*32 + w*2*ns;
  const unsigned short* kb = kbf + (size_t)bb * TTS * DKV;
  const unsigned short* vb = vbf + (size_t)bb * TTS * DKV;
  const float* kb32 = p.key + (size_t)bb * TTS * DKV;
  const float* vb32 = p.value + (size_t)bb * TTS * DKV;

  for (int c0 = 0; c0 < ns; c0 += 4) {
    float e[4], vx[4][4]; bool val[4]; int tt[4];
    #pragma unroll
    for (int j = 0; j < 4; ++j) {
      int jj = c0 + j;
      int jr = jj < ns ? jj : (ns - 1);
      int t = rbase + 2*jr + grp;
      int tc = t < TTS ? t : TTS - 1;
      val[j] = (jj < ns) && (t < len);
      tt[j] = t;
      size_t off = (size_t)tc*DKV + sub*4;
      float kx, ky, kz, kw;
      if constexpr (BF16) {
        ushort4 ku = *(const ushort4*)(kb + off);
        ushort4 vu = *(const ushort4*)(vb + off);
        kx = b2f(ku.x); ky = b2f(ku.y); kz = b2f(ku.z); kw = b2f(ku.w);
        vx[j][0] = b2f(vu.x); vx[j][1] = b2f(vu.y);
        vx[j][2] = b2f(vu.z); vx[j][3] = b2f(vu.w);
      } else {
        float4 k4 = *(const float4*)(kb32 + off);
        float4 v4 = *(const float4*)(vb32 + off);
        kx = k4.x; ky = k4.y; kz = k4.z; kw = k4.w;
        vx[j][0] = v4.x; vx[j][1] = v4.y; vx[j][2] = v4.z; vx[j][3] = v4.w;
      }
      float ep = q0*kx + q1*ky + q2*kz + q3*kw;
      ep += __shfl_xor(ep, 1); ep += __shfl_xor(ep, 2); ep += __shfl_xor(ep, 4);
      ep += __shfl_xor(ep, 8); ep += __shfl_xor(ep, 16);
      e[j] = val[j] ? ep * SCALE_F : -1e30f;
      if (bb == 0 && val[j] && sub == 0) wsE[tt[j]] = e[j];
    }
    float mc = fmaxf(fmaxf(e[0], e[1]), fmaxf(e[2], e[3]));
    float mn = fmaxf(m, mc);
    float al = __expf(m - mn);
    float pr[4];
    #pragma unroll
    for (int j = 0; j < 4; ++j) pr[j] = val[j] ? __expf(e[j] - mn) : 0.f;
    S = S*al + pr[0] + pr[1] + pr[2] + pr[3];
    ca.x = ca.x*al + pr[0]*vx[0][0] + pr[1]*vx[1][0] + pr[2]*vx[2][0] + pr[3]*vx[3][0];
    ca.y = ca.y*al + pr[0]*vx[0][1] + pr[1]*vx[1][1] + pr[2]*vx[2][1] + pr[3]*vx[3][1];
    ca.z = ca.z*al + pr[0]*vx[0][2] + pr[1]*vx[1][2] + pr[2]*vx[2][2] + pr[3]*vx[3][2];
    ca.w = ca.w*al + pr[0]*vx[0][3] + pr[1]*vx[1][3] + pr[2]*vx[2][3] + pr[3]*vx[3][3];
    m = mn;
  }
  attn_combine(sm, m, S, ca, lane, w, sub, grp, tid, pm2, pS2, pctx2, bb, s);
}

template<bool BF16>
__global__ void __launch_bounds__(NT, 4) decoder_kernel(Params p) {
  const int tid = threadIdx.x;
  const int bj = blockIdx.x;
  float* ws = p.ws;
  float* pm2 = ws + OFF_PM2;
  float* pS2 = ws + OFF_PS2;
  float* pctx2 = ws + OFF_PCTX2;
  float* wsE = ws + OFF_WSE;
  float* h1b0 = ws + OFF_H1;
  float* h1b1 = ws + OFF_H1 + HH1*BB;
  float* h2t0 = ws + OFF_H2T;
  float* h2t1 = ws + OFF_H2T + DKV*BB;
  unsigned* epA = (unsigned*)(ws + OFF_EP);
  unsigned* epB = epA + 256;
  unsigned* epC = epA + 320;
  unsigned short* kbf = (unsigned short*)(ws + OFF_KBF);
  unsigned short* vbf = (unsigned short*)(ws + OFF_VBF);

  __shared__ SMEM sm;

  // persistent registers: weights, biases, cell states
  float wr1[8] = {0,0,0,0,0,0,0,0};
  if (tid < 896) {
    #pragma unroll
    for (int r = 0; r < 8; ++r) {
      int grow = (r >> 1)*HH1 + 2*bj + (r & 1);
      wr1[r] = (tid < 384) ? p.Wih1[(size_t)grow*384 + tid]
                           : p.Whh1[(size_t)grow*HH1 + (tid - 384)];
    }
  }
  float wr2[8] = {0,0,0,0,0,0,0,0};
  if (bj < 64 && tid < 640) {
    #pragma unroll
    for (int r = 0; r < 8; ++r) {
      int grow = (r >> 1)*DKV + 2*bj + (r & 1);
      wr2[r] = (tid < 512) ? p.Wih2[(size_t)grow*HH1 + tid]
                           : p.Whh2[(size_t)grow*DKV + (tid - 512)];
    }
  }
  float bsum1 = 0.f, bsum2 = 0.f;
  if (tid < 512) {
    int r = tid >> 6;
    int g1 = (r >> 1)*HH1 + 2*bj + (r & 1);
    bsum1 = p.bih1[g1] + p.bhh1[g1];
    if (bj < 64) {
      int g2 = (r >> 1)*DKV + 2*bj + (r & 1);
      bsum2 = p.bih2[g2] + p.bhh2[g2];
    }
  }
  float c1r = 0.f, c2r = 0.f;

  // ---------------- setup ----------------
  // partition (computed redundantly per block -> no cross-block coherence needed)
  if (tid == 0) {
    int R_[64], nn[64], cp[64]; long G = 0;
    for (int b = 0; b < 64; ++b) { int L = p.enc_len[b]; R_[b] = (L + 31) >> 5; G += R_[b]; }
    int used = 0;
    for (int b = 0; b < 64; ++b) {
      int cap = R_[b] < 8 ? R_[b] : 8; cp[b] = cap;
      int v = (int)(((long)R_[b] * 256) / G);
      if (v < 1) v = 1; if (v > cap) v = cap;
      nn[b] = v; used += v;
    }
    while (used < 256) {
      int best = -1; float bv = -1.f;
      for (int b = 0; b < 64; ++b) if (nn[b] < cp[b]) {
        float v = (float)R_[b] / (float)nn[b];
        if (v > bv) { bv = v; best = b; }
      }
      if (best < 0) break;
      nn[best]++; used++;
    }
    while (used > 256) {
      int best = -1; float bv = 1e30f;
      for (int b = 0; b < 64; ++b) if (nn[b] > 1) {
        float v = (float)R_[b] / (float)nn[b];
        if (v < bv) { bv = v; best = b; }
      }
      nn[best]--; used--;
    }
    int* ip = (int*)sm.a.ctxT;
    for (int b = 0; b < 64; ++b) ip[b] = nn[b];
    int mybb = -1, mys = 0, j = 0;
    for (int b = 0; b < 64 && j <= bj; ++b)
      for (int s = 0; s < nn[b] && j <= bj; ++s) {
        if (j == bj) { mybb = b; mys = s; }
        ++j;
      }
    ip[64] = mybb; ip[65] = mys;
  }
  __syncthreads();
  int n_b_r, n0_r, bb_r, s_r, nown_r;
  {
    const int* ip = (const int*)sm.a.ctxT;
    n_b_r = ip[tid & 63]; n0_r = ip[0];
    bb_r = ip[64]; s_r = ip[65];
    nown_r = (bb_r >= 0) ? ip[bb_r] : 1;
  }
  __syncthreads();

  {
    int gid = bj*NT + tid;
    for (int idx = gid; idx < 81920; idx += NB*NT) ws[OFF_H1 + idx] = 0.f;  // h1 x2 + h2t x2
    if constexpr (BF16) {
      const int NG = (BB*TTS*DKV) / 8;
      for (int g = gid; g < NG; g += NB*NT) {
        const float4* src = (const float4*)p.key + (size_t)g*2;
        float4 a = src[0], bq = src[1];
        uint4 o;
        o.x = bfr(a.x)  | (bfr(a.y)  << 16);
        o.y = bfr(a.z)  | (bfr(a.w)  << 16);
        o.z = bfr(bq.x) | (bfr(bq.y) << 16);
        o.w = bfr(bq.z) | (bfr(bq.w) << 16);
        ((uint4*)kbf)[g] = o;
      }
      for (int g = gid; g < NG; g += NB*NT) {
        const float4* src = (const float4*)p.value + (size_t)g*2;
        float4 a = src[0], bq = src[1];
        uint4 o;
        o.x = bfr(a.x)  | (bfr(a.y)  << 16);
        o.y = bfr(a.z)  | (bfr(a.w)  << 16);
        o.z = bfr(bq.x) | (bfr(bq.y) << 16);
        o.w = bfr(bq.z) | (bfr(bq.w) << 16);
        ((uint4*)vbf)[g] = o;
      }
    }
    phase_attn_mean(p, pm2, pS2, pctx2, &sm, bj, tid);
  }
  post_ep(epC + bj, 1u);   // setup == C of step -1

  for (int i = 0; i <= LLS; ++i) {
    const int cur = i & 1;
    float* h1c = cur ? h1b1 : h1b0;
    const float* h1p = cur ? h1b0 : h1b1;
    float* h2tc = cur ? h2t1 : h2t0;
    const float* h2tp = cur ? h2t0 : h2t1;

    wait_ep(epC, 256, (unsigned)(i + 1));

    // ================= phase A =================
    // A0: combine slice partials (bypass loads) -> ctxT [d][b] in LDS
    {
      int b = tid & 63, dg = tid >> 6;
      int nc = (i == 0) ? 4 : n_b_r;
      float mv[8], sv[8];
      for (int s = 0; s < nc; ++s) { mv[s] = ldg_f(pm2 + b*8 + s); sv[s] = ldg_f(pS2 + b*8 + s); }
      float M = -1e30f;
      for (int s = 0; s < nc; ++s) M = fmaxf(M, mv[s]);
      float aa[8]; float Z = 0.f;
      for (int s = 0; s < nc; ++s) { aa[s] = __expf(mv[s] - M); Z += aa[s] * sv[s]; }
      float iZ = 1.f / Z;
      #pragma unroll
      for (int jj = 0; jj < 8; ++jj) {
        int d = dg + jj*16;
        float acc = 0.f;
        for (int s = 0; s < nc; ++s) acc += aa[s] * ldg_f(pctx2 + d*512 + b*8 + s);
        sm.a.ctxT[d*64 + b] = acc * iZ;
      }
    }
    if (i < LLS && tid < 896) {   // stage W1 rows from registers
      *(float4*)(sm.a.u.wt + tid*8)     = make_float4(wr1[0], wr1[1], wr1[2], wr1[3]);
      *(float4*)(sm.a.u.wt + tid*8 + 4) = make_float4(wr1[4], wr1[5], wr1[6], wr1[7]);
    }
    __syncthreads();

    if (i < LLS) {
      // A1: LSTM1 gates for h in {2bj, 2bj+1}
      {
        const int b0 = tid & 15, ks = tid >> 4;
        // preload recurrent h1 (bypass, issued back-to-back to pipeline)
        float hx[8][4];
        #pragma unroll
        for (int j = 0; j < 8; ++j) {
          const float* hp = h1p + (ks*8 + j)*64 + b0*4;
          hx[j][0] = ldg_f(hp); hx[j][1] = ldg_f(hp+1);
          hx[j][2] = ldg_f(hp+2); hx[j][3] = ldg_f(hp+3);
        }
        int idq[4];
        #pragma unroll
        for (int c = 0; c < 4; ++c) {
          int b = b0*4 + c;
          idq[c] = (i == 0) ? SOS_ID : p.y[b*LLS + (i-1)];
        }
        float acc[8][4];
        #pragma unroll
        for (int r = 0; r < 8; ++r) { acc[r][0]=0.f; acc[r][1]=0.f; acc[r][2]=0.f; acc[r][3]=0.f; }
        #pragma unroll
        for (int j = 0; j < 4; ++j) {             // emb segment (direct gather, L1-hot)
          int k = ks*4 + j;
          float4 x4 = make_float4(p.emb[(size_t)idq[0]*EEM + k], p.emb[(size_t)idq[1]*EEM + k],
                                  p.emb[(size_t)idq[2]*EEM + k], p.emb[(size_t)idq[3]*EEM + k]);
          mac8x4(acc, sm.a.u.wt, k, x4);
        }
        #pragma unroll
        for (int j = 0; j < 2; ++j) {             // ctx segment (LDS)
          int d = ks*2 + j;
          float4 x4 = *(const float4*)(sm.a.ctxT + d*64 + b0*4);
          mac8x4(acc, sm.a.u.wt, 256 + d, x4);
        }
        #pragma unroll
        for (int j = 0; j < 8; ++j) {             // h1 segment (preloaded)
          float4 x4 = make_float4(hx[j][0], hx[j][1], hx[j][2], hx[j][3]);
          mac8x4(acc, sm.a.u.wt, 384 + ks*8 + j, x4);
        }
        __syncthreads();
        gate_reduce_store(acc, sm.a.u.red, tid);
      }
      __syncthreads();
      if (tid < 512) {
        int r = tid >> 6, b = tid & 63;
        float s = 0.f;
        #pragma unroll
        for (int w2 = 0; w2 < 16; ++w2) s += sm.a.u.red[w2*512 + r*64 + b];
        s += bsum1;
        sm.a.u.red[r*64 + b] = s;
      }
      __syncthreads();
      if (tid < 128) {
        int hh = tid >> 6, b = tid & 63;
        int h = 2*bj + hh;
        float gi = sm.a.u.red[(hh+0)*64 + b];
        float gf = sm.a.u.red[(hh+2)*64 + b];
        float gg = sm.a.u.red[(hh+4)*64 + b];
        float go = sm.a.u.red[(hh+6)*64 + b];
        float cn = sigm(gf)*c1r + sigm(gi)*tanh_f(gg);
        float hn = sigm(go)*tanh_f(cn);
        c1r = cn;
        h1c[h*64 + b] = hn;
      }
    }

    if (i >= 1) {
      // A2: logits step i-1 (h2 prev via bypass, ctx via LDS, emb read-only)
      if (tid >= 960) {
        int ln = tid - 960;
        int oi = bj*8 + (ln >> 3);
        int sub = ln & 7;
        if (oi < BB*VVV) {
          int b = oi / VVV, v = oi - b*VVV;
          float a = 0.f;
          if (sub < 4) {
            #pragma unroll 8
            for (int e0 = 0; e0 < 32; ++e0) {
              int e = sub*32 + e0;
              a += ldg_f(h2tp + e*64 + b) * p.emb[v*EEM + e];
            }
          } else {
            #pragma unroll 8
            for (int e0 = 0; e0 < 32; ++e0) {
              int d = (sub - 4)*32 + e0;
              a += sm.a.ctxT[d*64 + b] * p.emb[v*EEM + 128 + d];
            }
          }
          a += __shfl_xor(a, 1); a += __shfl_xor(a, 2); a += __shfl_xor(a, 4);
          if (sub == 0) p.out[((size_t)b*LLS + (i-1))*VVV + v] = a + p.obias[v];
        }
      }
      // A3: attention plot row i-1
      if (tid >= 896 && tid < 904) {
        int t = bj*8 + (tid - 896);
        int len0 = p.enc_len[0];
        float v = 0.f;
        if (t < len0) {
          float M = -1e30f;
          for (int s = 0; s < n0_r; ++s) M = fmaxf(M, ldg_f(pm2 + s));
          float Z = 0.f;
          for (int s = 0; s < n0_r; ++s) Z += __expf(ldg_f(pm2 + s) - M) * ldg_f(pS2 + s);
          v = __expf(ldg_f(wsE + t) - M) / Z;
        }
        p.out[PRED_SZ + (size_t)(i-1)*TTS + t] = v;
      }
    }

    if (i == LLS) break;
    post_ep(epA + bj, (unsigned)(i + 1));

    // ================= phase B (blocks 0-63) =================
    if (bj < 64) {
      wait_ep(epA, 256, (unsigned)(i + 1));
      if (tid < 640) {
        *(float4*)(sm.a.u.wt + tid*8)     = make_float4(wr2[0], wr2[1], wr2[2], wr2[3]);
        *(float4*)(sm.a.u.wt + tid*8 + 4) = make_float4(wr2[4], wr2[5], wr2[6], wr2[7]);
      }
      __syncthreads();
      {
        const int b0 = tid & 15, ks = tid >> 4;
        // preload h1 (bypass) and h2 prev (bypass)
        float hx[8][4];
        #pragma unroll
        for (int j = 0; j < 8; ++j) {
          const float* hp = h1c + (ks*8 + j)*64 + b0*4;
          hx[j][0] = ldg_f(hp); hx[j][1] = ldg_f(hp+1);
          hx[j][2] = ldg_f(hp+2); hx[j][3] = ldg_f(hp+3);
        }
        float h2x[2][4];
        #pragma unroll
        for (int j = 0; j < 2; ++j) {
          const float* hp = h2tp + (ks*2 + j)*64 + b0*4;
          h2x[j][0] = ldg_f(hp); h2x[j][1] = ldg_f(hp+1);
          h2x[j][2] = ldg_f(hp+2); h2x[j][3] = ldg_f(hp+3);
        }
        float acc[8][4];
        #pragma unroll
        for (int r = 0; r < 8; ++r) { acc[r][0]=0.f; acc[r][1]=0.f; acc[r][2]=0.f; acc[r][3]=0.f; }
        #pragma unroll
        for (int j = 0; j < 8; ++j) {
          float4 x4 = make_float4(hx[j][0], hx[j][1], hx[j][2], hx[j][3]);
          mac8x4(acc, sm.a.u.wt, ks*8 + j, x4);
        }
        #pragma unroll
        for (int j = 0; j < 2; ++j) {
          float4 x4 = make_float4(h2x[j][0], h2x[j][1], h2x[j][2], h2x[j][3]);
          mac8x4(acc, sm.a.u.wt, 512 + ks*2 + j, x4);
        }
        __syncthreads();
        gate_reduce_store(acc, sm.a.u.red, tid);
      }
      __syncthreads();
      if (tid < 512) {
        int r = tid >> 6, b = tid & 63;
        float s = 0.f;
        #pragma unroll
        for (int w2 = 0; w2 < 16; ++w2) s += sm.a.u.red[w2*512 + r*64 + b];
        s += bsum2;
        sm.a.u.red[r*64 + b] = s;
      }
      __syncthreads();
      if (tid < 128) {
        int hh = tid >> 6, b = tid & 63;
        int d2 = 2*bj + hh;
        float gi = sm.a.u.red[(hh+0)*64 + b];
        float gf = sm.a.u.red[(hh+2)*64 + b];
        float gg = sm.a.u.red[(hh+4)*64 + b];
        float go = sm.a.u.red[(hh+6)*64 + b];
        float cn = sigm(gf)*c2r + sigm(gi)*tanh_f(gg);
        float hn = sigm(go)*tanh_f(cn);
        c2r = cn;
        h2tc[d2*64 + b] = hn;
      }
      post_ep(epB + bj, (unsigned)(i + 1));
    }

    // ================= phase C =================
    wait_ep(epB, 64, (unsigned)(i + 1));
    if (bb_r >= 0) {
      phase_attn_bal<BF16>(p, h2tc, kbf, vbf, pm2, pS2, pctx2, wsE,
                           bb_r, s_r, nown_r, &sm, tid);
    }
    post_ep(epC + bj, (unsigned)(i + 2));
  }
}

__global__ void init_ep_kernel(unsigned* ep) {
  int i = blockIdx.x * blockDim.x + threadIdx.x;
  if (i < 1024) ep[i] = 0u;
}

extern "C" void kernel_launch(void* const* d_in, const int* in_sizes, int n_in,
                              void* d_out, int out_size, void* d_ws, size_t ws_size,
                              hipStream_t stream) {
  Params prm;
  prm.key     = (const float*)d_in[0];
  prm.value   = (const float*)d_in[1];
  prm.enc_len = (const int*)d_in[2];
  prm.y       = (const int*)d_in[3];
  prm.emb     = (const float*)d_in[4];
  prm.Wih1    = (const float*)d_in[5];
  prm.Whh1    = (const float*)d_in[6];
  prm.bih1    = (const float*)d_in[7];
  prm.bhh1    = (const float*)d_in[8];
  prm.Wih2    = (const float*)d_in[9];
  prm.Whh2    = (const float*)d_in[10];
  prm.bih2    = (const float*)d_in[11];
  prm.bhh2    = (const float*)d_in[12];
  prm.obias   = (const float*)d_in[13];
  prm.out = (float*)d_out;
  prm.ws  = (float*)d_ws;

  unsigned* ep = (unsigned*)((float*)d_ws + OFF_EP);
  init_ep_kernel<<<4, 256, 0, stream>>>(ep);

  void* args[] = { &prm };
  if (ws_size >= WS_NEED_BYTES) {
    hipError_t e = hipLaunchCooperativeKernel((const void*)decoder_kernel<true>,
                                              dim3(NB), dim3(NT), args, 0, stream);
    if (e != hipSuccess) decoder_kernel<true><<<dim3(NB), dim3(NT), 0, stream>>>(prm);
  } else {
    hipError_t e = hipLaunchCooperativeKernel((const void*)decoder_kernel<false>,
                                              dim3(NB), dim3(NT), args, 0, stream);
    if (e != hipSuccess) decoder_kernel<false><<<dim3(NB), dim3(NT), 0, stream>>>(prm);
  }
}